// Round 2
// baseline (204.037 us; speedup 1.0000x reference)
//
#include <hip/hip_runtime.h>
#include <hip/hip_bf16.h>
#include <stdint.h>

// (B,T,EMB,H,D) = (2,2048,1024,16,64). I/O fp32, internal bf16 MFMA.
#define B_ 2
#define T_ 2048
#define EMB_ 1024
#define H_ 16
#define D_ 64
// 0.125 (D^-0.5) * log2(e): folded into Wq/bq so softmax uses native exp2.
#define QS_ 0.1803368801111f

typedef __attribute__((ext_vector_type(8))) __bf16 bf8_t;   // MFMA A/B frag
typedef __attribute__((ext_vector_type(8))) short s8_t;
typedef __attribute__((ext_vector_type(4))) short s4_t;
typedef __attribute__((ext_vector_type(4))) float f4_t;
typedef __attribute__((ext_vector_type(2))) unsigned int u32x2;

#if __has_builtin(__builtin_amdgcn_exp2f)
#define EXP2(x) __builtin_amdgcn_exp2f(x)
#else
#define EXP2(x) exp2f(x)
#endif

__device__ __forceinline__ short f2b(float f) {              // RNE
    union { float f; uint32_t u; } c; c.f = f;
    uint32_t r = (c.u + 0x7FFFu + ((c.u >> 16) & 1u)) >> 16;
    return (short)(uint16_t)r;
}

// two fp32 -> packed bf16 pair (no builtin on gfx950; RNE in HW)
__device__ __forceinline__ uint32_t cvtpk(float lo, float hi) {
    uint32_t r;
    asm volatile("v_cvt_pk_bf16_f32 %0, %1, %2" : "=v"(r) : "v"(lo), "v"(hi));
    return r;
}

// async global->LDS, 16B per lane. LDS dest = wave-uniform base + lane*16.
__device__ __forceinline__ void glds16(const void* g, void* l) {
    __builtin_amdgcn_global_load_lds(
        (const __attribute__((address_space(1))) unsigned int*)g,
        (__attribute__((address_space(3))) unsigned int*)l, 16, 0, 0);
}

// ---------------------------------------------------------------------------
// fp32 -> bf16 cast (same layout). total elems multiple of 1024.
// ---------------------------------------------------------------------------
__global__ __launch_bounds__(256)
void cast_f32_bf16(const float* __restrict__ in, short* __restrict__ outp) {
    const size_t i = ((size_t)blockIdx.x * 256 + threadIdx.x) * 4;
    f4_t v = *(const f4_t*)(in + i);
    s4_t r; r[0] = f2b(v[0]); r[1] = f2b(v[1]); r[2] = f2b(v[2]); r[3] = f2b(v[3]);
    *(s4_t*)(outp + i) = r;
}

// ---------------------------------------------------------------------------
// in[K][N] fp32 -> out[N][K] bf16, 64x64 LDS tiles.
// Output rows n < nscale get multiplied by sc (folds QK scale into Wq).
// grid: (N/64, K/64)
// ---------------------------------------------------------------------------
__global__ __launch_bounds__(256)
void transpose_f2b(const float* __restrict__ in, short* __restrict__ outp,
                   int K, int N, int nscale, float sc) {
    __shared__ short Ts[64][72];
    const int t = threadIdx.x;
    const int r = t >> 4, c = (t & 15) * 4;
    const int n0 = blockIdx.x * 64, k0 = blockIdx.y * 64;
    #pragma unroll
    for (int it = 0; it < 4; it++) {
        const int rr = it * 16 + r;
        f4_t v = *(const f4_t*)(in + (size_t)(k0 + rr) * N + n0 + c);
        #pragma unroll
        for (int j = 0; j < 4; j++) {
            const float s = (n0 + c + j < nscale) ? sc : 1.0f;
            Ts[c + j][rr] = f2b(v[j] * s);
        }
    }
    __syncthreads();
    #pragma unroll
    for (int it = 0; it < 4; it++) {
        const int rr = it * 16 + r;
        s4_t o;
        #pragma unroll
        for (int j = 0; j < 4; j++) o[j] = Ts[rr][c + j];
        *(s4_t*)(outp + (size_t)(n0 + rr) * K + k0 + c) = o;
    }
}

// ---------------------------------------------------------------------------
// V transpose: qkv[(b*T+t)*3072 + 2048 + h*64 + d] -> vt[(bh*64+d)*T + t]
// grid: (T/64, B*H)
// ---------------------------------------------------------------------------
__global__ __launch_bounds__(256)
void transpose_v(const short* __restrict__ qkv, short* __restrict__ vt) {
    __shared__ short Ts[64][72];
    const int t = threadIdx.x;
    const int r = t >> 4, c = (t & 15) * 4;
    const int bh = blockIdx.y, bb = bh >> 4, hh = bh & 15;
    const int t0 = blockIdx.x * 64;
    #pragma unroll
    for (int it = 0; it < 4; it++) {
        const int rr = it * 16 + r;
        s4_t v = *(const s4_t*)(qkv + (size_t)(bb * T_ + t0 + rr) * 3072 + 2048 + hh * 64 + c);
        #pragma unroll
        for (int j = 0; j < 4; j++) Ts[c + j][rr] = v[j];
    }
    __syncthreads();
    #pragma unroll
    for (int it = 0; it < 4; it++) {
        const int rr = it * 16 + r;
        s4_t o;
        #pragma unroll
        for (int j = 0; j < 4; j++) o[j] = Ts[rr][c + j];
        *(s4_t*)(vt + (size_t)(bh * 64 + rr) * T_ + t0 + c) = o;
    }
}

// ---------------------------------------------------------------------------
// GEMM C = A[M,K] @ Bt[N,K]^T + bias. bf16 in, BM=BN=128, BK=64, glds + XOR
// swizzle. outf32: fp32 C, else bf16. qsflag: bias cols < 1024 scaled by QS_.
// grid: (N/128, M/128), 256 threads.
// ---------------------------------------------------------------------------
__global__ __launch_bounds__(256)
void gemm_bt(const short* __restrict__ A, const short* __restrict__ Bt,
             const float* __restrict__ bias, short* __restrict__ Cb,
             float* __restrict__ Cf, int M, int N, int K, int outf32, int qsflag)
{
    __shared__ __align__(16) short As[128 * 64];
    __shared__ __align__(16) short Bs[128 * 64];

    const int t = threadIdx.x;
    const int L = t & 63, l16 = L & 15, quad = L >> 4;
    const int w = t >> 6, wm = w >> 1, wn = w & 1;
    const int n0 = blockIdx.x * 128, m0 = blockIdx.y * 128;

    f4_t acc[4][4];
    #pragma unroll
    for (int i = 0; i < 4; i++)
        #pragma unroll
        for (int j = 0; j < 4; j++) acc[i][j] = (f4_t){0.f, 0.f, 0.f, 0.f};

    for (int k0 = 0; k0 < K; k0 += 64) {
        __syncthreads();
        #pragma unroll
        for (int it = 0; it < 4; it++) {
            const int c = it * 256 + t;
            const int row = c >> 3, pc = c & 7;
            const int cc = pc ^ (row & 7);
            glds16(A + (size_t)(m0 + row) * K + k0 + cc * 8, &As[c * 8]);
            glds16(Bt + (size_t)(n0 + row) * K + k0 + cc * 8, &Bs[c * 8]);
        }
        asm volatile("s_waitcnt vmcnt(0)" ::: "memory");
        __syncthreads();

        #pragma unroll
        for (int kc = 0; kc < 2; kc++) {
            bf8_t a[4], b[4];
            #pragma unroll
            for (int i = 0; i < 4; i++) {
                const int row = wm * 64 + i * 16 + l16;
                const int ch = (kc * 4 + quad) ^ (row & 7);
                a[i] = *(const bf8_t*)(&As[row * 64 + ch * 8]);
            }
            #pragma unroll
            for (int j = 0; j < 4; j++) {
                const int row = wn * 64 + j * 16 + l16;
                const int ch = (kc * 4 + quad) ^ (row & 7);
                b[j] = *(const bf8_t*)(&Bs[row * 64 + ch * 8]);
            }
            #pragma unroll
            for (int i = 0; i < 4; i++)
                #pragma unroll
                for (int j = 0; j < 4; j++)
                    acc[i][j] = __builtin_amdgcn_mfma_f32_16x16x32_bf16(a[i], b[j], acc[i][j], 0, 0, 0);
        }
    }

    #pragma unroll
    for (int j = 0; j < 4; j++) {
        const int n = n0 + wn * 64 + j * 16 + l16;
        float bv = bias[n];
        if (qsflag && n < 1024) bv *= QS_;
        #pragma unroll
        for (int i = 0; i < 4; i++) {
            #pragma unroll
            for (int r = 0; r < 4; r++) {
                const int m = m0 + wm * 64 + i * 16 + quad * 4 + r;
                const float val = acc[i][j][r] + bv;
                if (outf32) Cf[(size_t)m * N + n] = val;
                else        Cb[(size_t)m * N + n] = f2b(val);
            }
        }
    }
}

// ---------------------------------------------------------------------------
// Flash causal attention v5. Block = 128 q-rows of one (b,h); 4 waves x 32
// rows (2 groups of 16). K-tile = 64 keys, double-buffered, counted vmcnt,
// raw s_barrier. K- and V-fragments are read from LDS ONCE per tile and held
// in registers across both row groups -> per-work LDS read traffic -44%,
// barriers/stage per work halved vs the 64-row block (this was the r1
// bottleneck: ~50-60% LDS-BW busy on a barrier-locked critical path).
// Swapped QK^T (mfma(K,Q) -> S^T), no-shift exp2 softmax (exact), P packed
// via v_cvt_pk_bf16_f32 + swizzled ds_write_b64, row-sum l via ones-MFMA.
// LDS = 48KB. grid: 512 blocks (2/CU), heavy q-tiles first.
// qkv: [B*T,3072] bf16 (Q pre-scaled by QS_). vt: [B*H*64, T]. ab: [B*T,1024].
// ---------------------------------------------------------------------------
__global__ __launch_bounds__(256)
void attn_kernel(const short* __restrict__ qkv, const short* __restrict__ vt,
                 short* __restrict__ ab)
{
    __shared__ __align__(16) short Ks[2][64 * 64];
    __shared__ __align__(16) short Vs[2][64 * 64];
    __shared__ __align__(16) short Ps[4][2 * 1024];  // per wave: 2 groups x 16 rows x 64 keys

    const int t = threadIdx.x;
    const int L = t & 63, l16 = L & 15, quad = L >> 4;
    const int w = t >> 6;

    const int qi = 15 - (blockIdx.x >> 5);   // heavy 128-row q-tiles first
    const int bh = blockIdx.x & 31;
    const int bb = bh >> 4, hh = bh & 15;
    const int qb = qi * 128;
    const int wrow = qb + w * 32;            // wave's first q-row (32 rows)

    // Q B-frags for both 16-row groups (Q pre-scaled by QS_)
    const size_t qoff0 = (size_t)(bb * T_ + wrow + l16) * 3072 + hh * 64;
    const size_t qoff1 = qoff0 + (size_t)16 * 3072;
    const bf8_t q0a = *(const bf8_t*)(qkv + qoff0 + quad * 8);
    const bf8_t q0b = *(const bf8_t*)(qkv + qoff0 + 32 + quad * 8);
    const bf8_t q1a = *(const bf8_t*)(qkv + qoff1 + quad * 8);
    const bf8_t q1b = *(const bf8_t*)(qkv + qoff1 + 32 + quad * 8);

    // all-ones B-frag (bf16 1.0) for the l row-sum MFMA
    s8_t os_;
    #pragma unroll
    for (int i = 0; i < 8; i++) os_[i] = (short)0x3F80;
    const bf8_t ones = *(const bf8_t*)&os_;

    f4_t lacc0 = {0.f, 0.f, 0.f, 0.f}, lacc1 = {0.f, 0.f, 0.f, 0.f};
    f4_t o_acc0[4], o_acc1[4];
    #pragma unroll
    for (int nc = 0; nc < 4; nc++) {
        o_acc0[nc] = (f4_t){0.f, 0.f, 0.f, 0.f};
        o_acc1[nc] = (f4_t){0.f, 0.f, 0.f, 0.f};
    }

#define STAGE(ktile, buf)                                                      \
    {                                                                          \
        const int ktb_ = (ktile) * 64;                                         \
        _Pragma("unroll")                                                      \
        for (int it = 0; it < 2; it++) {                                       \
            const int c = it * 256 + t;                                        \
            const int row = c >> 3, pc = c & 7;                                \
            const int cc = pc ^ (row & 7);                                     \
            glds16(qkv + (size_t)(bb * T_ + ktb_ + row) * 3072 + 1024 + hh * 64 + cc * 8, \
                   &Ks[buf][c * 8]);                                           \
            glds16(vt + (size_t)(bh * 64 + row) * T_ + ktb_ + cc * 8,          \
                   &Vs[buf][c * 8]);                                           \
        }                                                                      \
    }

    const int nkt = 2 * qi + 2;              // keys 0 .. qb+127
    STAGE(0, 0);
    for (int kt = 0; kt < nkt; kt++) {
        const int cur = kt & 1;
        if (kt + 1 < nkt) {
            STAGE(kt + 1, cur ^ 1);                    // prefetch next tile
            asm volatile("s_waitcnt vmcnt(4)" ::: "memory");   // kt's 4 landed
        } else {
            asm volatile("s_waitcnt vmcnt(0)" ::: "memory");
        }
        __builtin_amdgcn_s_barrier();                  // all waves' kt landed

        const int ktb = kt * 64;
        if (ktb <= wrow + 31) {                        // wave-uniform causal skip
            const bool do0 = (ktb <= wrow + 15);       // group 0 active?
            char* const psb = (char*)&Ps[w][0];
            const int swz = (l16 & 7) << 4;

            // K frags once, reused by both row groups (32 VGPRs)
            bf8_t k0f[4], k1f[4];
            #pragma unroll
            for (int nh = 0; nh < 4; nh++) {
                const int key = nh * 16 + l16;
                const int ch0 = quad ^ (key & 7);
                const int ch1 = (4 + quad) ^ (key & 7);
                k0f[nh] = *(const bf8_t*)(&Ks[cur][key * 64 + ch0 * 8]);
                k1f[nh] = *(const bf8_t*)(&Ks[cur][key * 64 + ch1 * 8]);
            }

            // ---- group 0: S^T, softmax, P write ----
            if (do0) {
                const int qrow = wrow + l16;
                const bool domask = (ktb + 63 > wrow);
                #pragma unroll
                for (int nh = 0; nh < 4; nh++) {
                    f4_t z = {0.f, 0.f, 0.f, 0.f};
                    z = __builtin_amdgcn_mfma_f32_16x16x32_bf16(k0f[nh], q0a, z, 0, 0, 0);
                    z = __builtin_amdgcn_mfma_f32_16x16x32_bf16(k1f[nh], q0b, z, 0, 0, 0);
                    float v0 = z[0], v1 = z[1], v2 = z[2], v3 = z[3];
                    if (domask) {
                        const int keyb = ktb + nh * 16 + quad * 4;
                        if (keyb     > qrow) v0 = -1e30f;
                        if (keyb + 1 > qrow) v1 = -1e30f;
                        if (keyb + 2 > qrow) v2 = -1e30f;
                        if (keyb + 3 > qrow) v3 = -1e30f;
                    }
                    u32x2 pk2;
                    pk2.x = cvtpk(EXP2(v0), EXP2(v1));
                    pk2.y = cvtpk(EXP2(v2), EXP2(v3));
                    *(u32x2*)(psb + l16 * 128 + ((nh * 32 + quad * 8) ^ swz)) = pk2;
                }
            }

            // ---- group 1: S^T, softmax, P write (K frags reused) ----
            {
                const int wrow1 = wrow + 16;
                const int qrow = wrow1 + l16;
                const bool domask = (ktb + 63 > wrow1);
                #pragma unroll
                for (int nh = 0; nh < 4; nh++) {
                    f4_t z = {0.f, 0.f, 0.f, 0.f};
                    z = __builtin_amdgcn_mfma_f32_16x16x32_bf16(k0f[nh], q1a, z, 0, 0, 0);
                    z = __builtin_amdgcn_mfma_f32_16x16x32_bf16(k1f[nh], q1b, z, 0, 0, 0);
                    float v0 = z[0], v1 = z[1], v2 = z[2], v3 = z[3];
                    if (domask) {
                        const int keyb = ktb + nh * 16 + quad * 4;
                        if (keyb     > qrow) v0 = -1e30f;
                        if (keyb + 1 > qrow) v1 = -1e30f;
                        if (keyb + 2 > qrow) v2 = -1e30f;
                        if (keyb + 3 > qrow) v3 = -1e30f;
                    }
                    u32x2 pk2;
                    pk2.x = cvtpk(EXP2(v0), EXP2(v1));
                    pk2.y = cvtpk(EXP2(v2), EXP2(v3));
                    *(u32x2*)(psb + 2048 + l16 * 128 + ((nh * 32 + quad * 8) ^ swz)) = pk2;
                }
            }
            asm volatile("s_waitcnt lgkmcnt(0)" ::: "memory");

            // V frags once, reused by both row groups (32 VGPRs)
            bf8_t v0f[4], v1f[4];
            #pragma unroll
            for (int nc = 0; nc < 4; nc++) {
                const int d = nc * 16 + l16;
                const int ch0 = quad ^ (d & 7);
                const int ch1 = (4 + quad) ^ (d & 7);
                v0f[nc] = *(const bf8_t*)(&Vs[cur][d * 64 + ch0 * 8]);
                v1f[nc] = *(const bf8_t*)(&Vs[cur][d * 64 + ch1 * 8]);
            }

            if (do0) {
                const bf8_t pa0 = *(const bf8_t*)(psb + l16 * 128 + ((quad * 16) ^ swz));
                const bf8_t pa1 = *(const bf8_t*)(psb + l16 * 128 + ((64 + quad * 16) ^ swz));
                lacc0 = __builtin_amdgcn_mfma_f32_16x16x32_bf16(pa0, ones, lacc0, 0, 0, 0);
                lacc0 = __builtin_amdgcn_mfma_f32_16x16x32_bf16(pa1, ones, lacc0, 0, 0, 0);
                #pragma unroll
                for (int nc = 0; nc < 4; nc++) {
                    o_acc0[nc] = __builtin_amdgcn_mfma_f32_16x16x32_bf16(pa0, v0f[nc], o_acc0[nc], 0, 0, 0);
                    o_acc0[nc] = __builtin_amdgcn_mfma_f32_16x16x32_bf16(pa1, v1f[nc], o_acc0[nc], 0, 0, 0);
                }
            }
            {
                const bf8_t pa0 = *(const bf8_t*)(psb + 2048 + l16 * 128 + ((quad * 16) ^ swz));
                const bf8_t pa1 = *(const bf8_t*)(psb + 2048 + l16 * 128 + ((64 + quad * 16) ^ swz));
                lacc1 = __builtin_amdgcn_mfma_f32_16x16x32_bf16(pa0, ones, lacc1, 0, 0, 0);
                lacc1 = __builtin_amdgcn_mfma_f32_16x16x32_bf16(pa1, ones, lacc1, 0, 0, 0);
                #pragma unroll
                for (int nc = 0; nc < 4; nc++) {
                    o_acc1[nc] = __builtin_amdgcn_mfma_f32_16x16x32_bf16(pa0, v0f[nc], o_acc1[nc], 0, 0, 0);
                    o_acc1[nc] = __builtin_amdgcn_mfma_f32_16x16x32_bf16(pa1, v1f[nc], o_acc1[nc], 0, 0, 0);
                }
            }
        }
        __builtin_amdgcn_s_barrier();   // protect buf cur before next prefetch
    }
#undef STAGE

    // epilogue: O / l (lacc rows == o_acc rows; no cross-lane work needed)
    #pragma unroll
    for (int r = 0; r < 4; r++) {
        const float rl0 = __builtin_amdgcn_rcpf(lacc0[r]);
        const float rl1 = __builtin_amdgcn_rcpf(lacc1[r]);
        const int row0 = wrow + quad * 4 + r;
        const int row1 = wrow + 16 + quad * 4 + r;
        #pragma unroll
        for (int nc = 0; nc < 4; nc++) {
            ab[(size_t)(bb * T_ + row0) * 1024 + hh * 64 + nc * 16 + l16] =
                f2b(o_acc0[nc][r] * rl0);
            ab[(size_t)(bb * T_ + row1) * 1024 + hh * 64 + nc * 16 + l16] =
                f2b(o_acc1[nc][r] * rl1);
        }
    }
}

extern "C" void kernel_launch(void* const* d_in, const int* in_sizes, int n_in,
                              void* d_out, int out_size, void* d_ws, size_t ws_size,
                              hipStream_t stream) {
    const float* x    = (const float*)d_in[0];   // [4096,1024]
    const float* Wqkv = (const float*)d_in[1];   // [1024,3072]
    const float* bqkv = (const float*)d_in[2];   // [3072]
    const float* Wout = (const float*)d_in[3];   // [1024,1024]
    const float* bout = (const float*)d_in[4];   // [1024]
    float* out = (float*)d_out;                  // [4096,1024] fp32

    short* ws   = (short*)d_ws;
    short* xb   = ws;                                  // 4096*1024 (later: ab)
    short* wqt  = xb + (size_t)4096 * 1024;            // 3072*1024 (later: WoutT)
    short* qkvt = wqt + (size_t)3072 * 1024;           // 4096*3072
    short* vt   = (short*)d_out;                       // bf16 scratch in d_out
    short* ab   = xb;                                  // reuse xb after gemm_qkv

    // 1) cast x; transpose Wqkv (Q-rows pre-scaled by QS_ = 0.125*log2e)
    cast_f32_bf16<<<4096, 256, 0, stream>>>(x, xb);
    transpose_f2b<<<dim3(48, 16), 256, 0, stream>>>(Wqkv, wqt, 1024, 3072, 1024, QS_);

    // 2) QKV projection -> qkvt [4096][3072] bf16 (Q cols scaled, incl. bias)
    gemm_bt<<<dim3(24, 32), 256, 0, stream>>>(xb, wqt, bqkv, qkvt, nullptr,
                                              4096, 3072, 1024, 0, 1);

    // 3) V transpose -> vt ; Wout transpose (reuses wqt)
    transpose_v<<<dim3(32, 32), 256, 0, stream>>>(qkvt, vt);
    transpose_f2b<<<dim3(16, 16), 256, 0, stream>>>(Wout, wqt, 1024, 1024, 0, 1.0f);

    // 4) causal flash attention -> ab (128-row q-blocks, heavy first)
    attn_kernel<<<512, 256, 0, stream>>>(qkvt, vt, ab);

    // 5) output projection -> fp32 d_out (overwrites vt scratch)
    gemm_bt<<<dim3(8, 32), 256, 0, stream>>>(ab, wqt, bout, nullptr, out,
                                             4096, 1024, 1024, 1, 0);
}

// Round 3
// 181.925 us; speedup vs baseline: 1.1215x; 1.1215x over previous
//
#include <hip/hip_runtime.h>
#include <hip/hip_bf16.h>
#include <stdint.h>

// (B,T,EMB,H,D) = (2,2048,1024,16,64). I/O fp32, internal bf16 MFMA.
#define B_ 2
#define T_ 2048
#define EMB_ 1024
#define H_ 16
#define D_ 64
// 0.125 (D^-0.5) * log2(e): folded into Wq/bq so softmax uses native exp2.
#define QS_ 0.1803368801111f

typedef __attribute__((ext_vector_type(8))) __bf16 bf8_t;   // MFMA A/B frag
typedef __attribute__((ext_vector_type(8))) short s8_t;
typedef __attribute__((ext_vector_type(4))) short s4_t;
typedef __attribute__((ext_vector_type(4))) float f4_t;
typedef __attribute__((ext_vector_type(2))) unsigned int u32x2;

#if __has_builtin(__builtin_amdgcn_exp2f)
#define EXP2(x) __builtin_amdgcn_exp2f(x)
#else
#define EXP2(x) exp2f(x)
#endif

__device__ __forceinline__ short f2b(float f) {              // RNE
    union { float f; uint32_t u; } c; c.f = f;
    uint32_t r = (c.u + 0x7FFFu + ((c.u >> 16) & 1u)) >> 16;
    return (short)(uint16_t)r;
}

// two fp32 -> packed bf16 pair (no builtin on gfx950; RNE in HW)
__device__ __forceinline__ uint32_t cvtpk(float lo, float hi) {
    uint32_t r;
    asm volatile("v_cvt_pk_bf16_f32 %0, %1, %2" : "=v"(r) : "v"(lo), "v"(hi));
    return r;
}

// async global->LDS, 16B per lane. LDS dest = wave-uniform base + lane*16.
__device__ __forceinline__ void glds16(const void* g, void* l) {
    __builtin_amdgcn_global_load_lds(
        (const __attribute__((address_space(1))) unsigned int*)g,
        (__attribute__((address_space(3))) unsigned int*)l, 16, 0, 0);
}

// ---------------------------------------------------------------------------
// fp32 -> bf16 cast (same layout). total elems multiple of 1024.
// ---------------------------------------------------------------------------
__global__ __launch_bounds__(256)
void cast_f32_bf16(const float* __restrict__ in, short* __restrict__ outp) {
    const size_t i = ((size_t)blockIdx.x * 256 + threadIdx.x) * 4;
    f4_t v = *(const f4_t*)(in + i);
    s4_t r; r[0] = f2b(v[0]); r[1] = f2b(v[1]); r[2] = f2b(v[2]); r[3] = f2b(v[3]);
    *(s4_t*)(outp + i) = r;
}

// ---------------------------------------------------------------------------
// in[K][N] fp32 -> out[N][K] bf16, 64x64 LDS tiles.
// Output rows n < nscale get multiplied by sc (folds QK scale into Wq).
// grid: (N/64, K/64)
// ---------------------------------------------------------------------------
__global__ __launch_bounds__(256)
void transpose_f2b(const float* __restrict__ in, short* __restrict__ outp,
                   int K, int N, int nscale, float sc) {
    __shared__ short Ts[64][72];
    const int t = threadIdx.x;
    const int r = t >> 4, c = (t & 15) * 4;
    const int n0 = blockIdx.x * 64, k0 = blockIdx.y * 64;
    #pragma unroll
    for (int it = 0; it < 4; it++) {
        const int rr = it * 16 + r;
        f4_t v = *(const f4_t*)(in + (size_t)(k0 + rr) * N + n0 + c);
        #pragma unroll
        for (int j = 0; j < 4; j++) {
            const float s = (n0 + c + j < nscale) ? sc : 1.0f;
            Ts[c + j][rr] = f2b(v[j] * s);
        }
    }
    __syncthreads();
    #pragma unroll
    for (int it = 0; it < 4; it++) {
        const int rr = it * 16 + r;
        s4_t o;
        #pragma unroll
        for (int j = 0; j < 4; j++) o[j] = Ts[rr][c + j];
        *(s4_t*)(outp + (size_t)(n0 + rr) * K + k0 + c) = o;
    }
}

// ---------------------------------------------------------------------------
// V transpose: qkv[(b*T+t)*3072 + 2048 + h*64 + d] -> vt[(bh*64+d)*T + t]
// grid: (T/64, B*H)
// ---------------------------------------------------------------------------
__global__ __launch_bounds__(256)
void transpose_v(const short* __restrict__ qkv, short* __restrict__ vt) {
    __shared__ short Ts[64][72];
    const int t = threadIdx.x;
    const int r = t >> 4, c = (t & 15) * 4;
    const int bh = blockIdx.y, bb = bh >> 4, hh = bh & 15;
    const int t0 = blockIdx.x * 64;
    #pragma unroll
    for (int it = 0; it < 4; it++) {
        const int rr = it * 16 + r;
        s4_t v = *(const s4_t*)(qkv + (size_t)(bb * T_ + t0 + rr) * 3072 + 2048 + hh * 64 + c);
        #pragma unroll
        for (int j = 0; j < 4; j++) Ts[c + j][rr] = v[j];
    }
    __syncthreads();
    #pragma unroll
    for (int it = 0; it < 4; it++) {
        const int rr = it * 16 + r;
        s4_t o;
        #pragma unroll
        for (int j = 0; j < 4; j++) o[j] = Ts[rr][c + j];
        *(s4_t*)(vt + (size_t)(bh * 64 + rr) * T_ + t0 + c) = o;
    }
}

// ---------------------------------------------------------------------------
// GEMM C = A[M,K] @ Bt[N,K]^T + bias. bf16 in, BM=BN=128, BK=64, glds + XOR
// swizzle. outf32: fp32 C, else bf16. qsflag: bias cols < 1024 scaled by QS_.
// grid: (N/128, M/128), 256 threads.
// ---------------------------------------------------------------------------
__global__ __launch_bounds__(256)
void gemm_bt(const short* __restrict__ A, const short* __restrict__ Bt,
             const float* __restrict__ bias, short* __restrict__ Cb,
             float* __restrict__ Cf, int M, int N, int K, int outf32, int qsflag)
{
    __shared__ __align__(16) short As[128 * 64];
    __shared__ __align__(16) short Bs[128 * 64];

    const int t = threadIdx.x;
    const int L = t & 63, l16 = L & 15, quad = L >> 4;
    const int w = t >> 6, wm = w >> 1, wn = w & 1;
    const int n0 = blockIdx.x * 128, m0 = blockIdx.y * 128;

    f4_t acc[4][4];
    #pragma unroll
    for (int i = 0; i < 4; i++)
        #pragma unroll
        for (int j = 0; j < 4; j++) acc[i][j] = (f4_t){0.f, 0.f, 0.f, 0.f};

    for (int k0 = 0; k0 < K; k0 += 64) {
        __syncthreads();
        #pragma unroll
        for (int it = 0; it < 4; it++) {
            const int c = it * 256 + t;
            const int row = c >> 3, pc = c & 7;
            const int cc = pc ^ (row & 7);
            glds16(A + (size_t)(m0 + row) * K + k0 + cc * 8, &As[c * 8]);
            glds16(Bt + (size_t)(n0 + row) * K + k0 + cc * 8, &Bs[c * 8]);
        }
        asm volatile("s_waitcnt vmcnt(0)" ::: "memory");
        __syncthreads();

        #pragma unroll
        for (int kc = 0; kc < 2; kc++) {
            bf8_t a[4], b[4];
            #pragma unroll
            for (int i = 0; i < 4; i++) {
                const int row = wm * 64 + i * 16 + l16;
                const int ch = (kc * 4 + quad) ^ (row & 7);
                a[i] = *(const bf8_t*)(&As[row * 64 + ch * 8]);
            }
            #pragma unroll
            for (int j = 0; j < 4; j++) {
                const int row = wn * 64 + j * 16 + l16;
                const int ch = (kc * 4 + quad) ^ (row & 7);
                b[j] = *(const bf8_t*)(&Bs[row * 64 + ch * 8]);
            }
            #pragma unroll
            for (int i = 0; i < 4; i++)
                #pragma unroll
                for (int j = 0; j < 4; j++)
                    acc[i][j] = __builtin_amdgcn_mfma_f32_16x16x32_bf16(a[i], b[j], acc[i][j], 0, 0, 0);
        }
    }

    #pragma unroll
    for (int j = 0; j < 4; j++) {
        const int n = n0 + wn * 64 + j * 16 + l16;
        float bv = bias[n];
        if (qsflag && n < 1024) bv *= QS_;
        #pragma unroll
        for (int i = 0; i < 4; i++) {
            #pragma unroll
            for (int r = 0; r < 4; r++) {
                const int m = m0 + wm * 64 + i * 16 + quad * 4 + r;
                const float val = acc[i][j][r] + bv;
                if (outf32) Cf[(size_t)m * N + n] = val;
                else        Cb[(size_t)m * N + n] = f2b(val);
            }
        }
    }
}

// ---------------------------------------------------------------------------
// GEMM (output projection): C = A[M,K] @ Bt[N,K]^T + bias, fp32 out.
// BM=128, BN=64, BK=64 -> grid (N/64, M/128) = 512 blocks (2/CU), LDS 48KB
// double-buffered with counted-vmcnt prefetch (attn-style: stage kt+1, wait
// vmcnt(6) for kt, raw barriers, never drain mid-loop). The old 128x128 grid
// was 256 blocks = 1 block/CU with a serial drain-per-K-step: latency fully
// exposed. 4 waves stacked on M (each 32 rows x 64 cols, acc[2][4]).
// ---------------------------------------------------------------------------
__global__ __launch_bounds__(256)
void gemm_bt_n64(const short* __restrict__ A, const short* __restrict__ Bt,
                 const float* __restrict__ bias, float* __restrict__ Cf,
                 int M, int N, int K)
{
    __shared__ __align__(16) short As[2][128 * 64];
    __shared__ __align__(16) short Bs[2][64 * 64];

    const int t = threadIdx.x;
    const int L = t & 63, l16 = L & 15, quad = L >> 4;
    const int w = t >> 6;                       // wave id = M-slice
    const int n0 = blockIdx.x * 64, m0 = blockIdx.y * 128;

    f4_t acc[2][4];
    #pragma unroll
    for (int i = 0; i < 2; i++)
        #pragma unroll
        for (int j = 0; j < 4; j++) acc[i][j] = (f4_t){0.f, 0.f, 0.f, 0.f};

#define GSTAGE(kt_, buf_)                                                      \
    {                                                                          \
        const int k0_ = (kt_) * 64;                                            \
        _Pragma("unroll")                                                      \
        for (int it = 0; it < 4; it++) {                                       \
            const int c = it * 256 + t;                                        \
            const int row = c >> 3, pc = c & 7;                                \
            const int cc = pc ^ (row & 7);                                     \
            glds16(A + (size_t)(m0 + row) * K + k0_ + cc * 8, &As[buf_][c * 8]); \
        }                                                                      \
        _Pragma("unroll")                                                      \
        for (int it = 0; it < 2; it++) {                                       \
            const int c = it * 256 + t;                                        \
            const int row = c >> 3, pc = c & 7;                                \
            const int cc = pc ^ (row & 7);                                     \
            glds16(Bt + (size_t)(n0 + row) * K + k0_ + cc * 8, &Bs[buf_][c * 8]); \
        }                                                                      \
    }

    const int nkt = K >> 6;
    GSTAGE(0, 0);
    for (int kt = 0; kt < nkt; kt++) {
        const int cur = kt & 1;
        if (kt + 1 < nkt) {
            GSTAGE(kt + 1, cur ^ 1);                   // prefetch next K-tile
            asm volatile("s_waitcnt vmcnt(6)" ::: "memory");   // kt's 6 landed
        } else {
            asm volatile("s_waitcnt vmcnt(0)" ::: "memory");
        }
        __builtin_amdgcn_s_barrier();

        #pragma unroll
        for (int kc = 0; kc < 2; kc++) {
            bf8_t a[2], b[4];
            #pragma unroll
            for (int i = 0; i < 2; i++) {
                const int row = w * 32 + i * 16 + l16;
                const int ch = (kc * 4 + quad) ^ (row & 7);
                a[i] = *(const bf8_t*)(&As[cur][row * 64 + ch * 8]);
            }
            #pragma unroll
            for (int j = 0; j < 4; j++) {
                const int row = j * 16 + l16;
                const int ch = (kc * 4 + quad) ^ (row & 7);
                b[j] = *(const bf8_t*)(&Bs[cur][row * 64 + ch * 8]);
            }
            #pragma unroll
            for (int i = 0; i < 2; i++)
                #pragma unroll
                for (int j = 0; j < 4; j++)
                    acc[i][j] = __builtin_amdgcn_mfma_f32_16x16x32_bf16(a[i], b[j], acc[i][j], 0, 0, 0);
        }
        __builtin_amdgcn_s_barrier();   // protect buf cur before next prefetch
    }
#undef GSTAGE

    #pragma unroll
    for (int j = 0; j < 4; j++) {
        const int n = n0 + j * 16 + l16;
        const float bv = bias[n];
        #pragma unroll
        for (int i = 0; i < 2; i++) {
            #pragma unroll
            for (int r = 0; r < 4; r++) {
                const int m = m0 + w * 32 + i * 16 + quad * 4 + r;
                Cf[(size_t)m * N + n] = acc[i][j][r] + bv;
            }
        }
    }
}

// ---------------------------------------------------------------------------
// Flash causal attention v4 (r1-proven, 44.5us). Block = 64 q-rows of one
// (b,h); 4 waves x 16 rows. K-tile = 64 keys, double-buffered with counted
// vmcnt (stage kt+1 before waiting on kt; never drain to 0 mid-loop; raw
// s_barrier). Swapped QK^T (mfma(K,Q) -> S^T). No-shift exp2 softmax
// (exact). P packed via v_cvt_pk_bf16_f32 + swizzled ds_write_b64; row-sum
// l via ones-MFMA. LDS = 40960 B -> 4 blocks/CU (the latency-hiding
// resource: r2's 128-row variant halved blocks/CU and regressed 35%).
// qkv: [B*T,3072] bf16 (Q pre-scaled by QS_). vt: [B*H*64, T]. ab: [B*T,1024].
// ---------------------------------------------------------------------------
__global__ __launch_bounds__(256)
void attn_kernel(const short* __restrict__ qkv, const short* __restrict__ vt,
                 short* __restrict__ ab)
{
    __shared__ __align__(16) short Ks[2][64 * 64];
    __shared__ __align__(16) short Vs[2][64 * 64];
    __shared__ __align__(16) short Ps[4][16 * 64];

    const int t = threadIdx.x;
    const int L = t & 63, l16 = L & 15, quad = L >> 4;
    const int w = t >> 6;

    const int qi = 31 - (blockIdx.x >> 5);   // heavy q-tiles first
    const int bh = blockIdx.x & 31;
    const int bb = bh >> 4, hh = bh & 15;
    const int qb = qi * 64;
    const int wrow = qb + w * 16;            // wave's first q-row
    const int qrow = wrow + l16;             // this lane's q-row (S^T col)

    // Q B-frags for this wave's 16 rows (Q already scaled by QS_*log2e)
    const size_t qoff = (size_t)(bb * T_ + wrow + l16) * 3072 + hh * 64;
    const bf8_t qa0 = *(const bf8_t*)(qkv + qoff + quad * 8);
    const bf8_t qa1 = *(const bf8_t*)(qkv + qoff + 32 + quad * 8);

    // all-ones B-frag (bf16 1.0) for the l row-sum MFMA
    s8_t os_;
    #pragma unroll
    for (int i = 0; i < 8; i++) os_[i] = (short)0x3F80;
    const bf8_t ones = *(const bf8_t*)&os_;

    f4_t lacc = {0.f, 0.f, 0.f, 0.f};
    f4_t o_acc[4];
    #pragma unroll
    for (int nc = 0; nc < 4; nc++) o_acc[nc] = (f4_t){0.f, 0.f, 0.f, 0.f};

#define STAGE(ktile, buf)                                                      \
    {                                                                          \
        const int ktb_ = (ktile) * 64;                                         \
        _Pragma("unroll")                                                      \
        for (int it = 0; it < 2; it++) {                                       \
            const int c = it * 256 + t;                                        \
            const int row = c >> 3, pc = c & 7;                                \
            const int cc = pc ^ (row & 7);                                     \
            glds16(qkv + (size_t)(bb * T_ + ktb_ + row) * 3072 + 1024 + hh * 64 + cc * 8, \
                   &Ks[buf][c * 8]);                                           \
            glds16(vt + (size_t)(bh * 64 + row) * T_ + ktb_ + cc * 8,          \
                   &Vs[buf][c * 8]);                                           \
        }                                                                      \
    }

    const int nkt = qi + 1;
    STAGE(0, 0);
    for (int kt = 0; kt < nkt; kt++) {
        const int cur = kt & 1;
        if (kt + 1 < nkt) {
            STAGE(kt + 1, cur ^ 1);                    // prefetch next tile
            asm volatile("s_waitcnt vmcnt(4)" ::: "memory");   // kt's 4 landed
        } else {
            asm volatile("s_waitcnt vmcnt(0)" ::: "memory");
        }
        __builtin_amdgcn_s_barrier();                  // all waves' kt landed

        if (kt * 64 <= wrow + 15) {                    // wave-uniform causal skip
            const int ktb = kt * 64;
            const bool domask = (ktb + 63 > wrow);

            // S^T = K Q^T : 64 keys x 16 q-rows (swapped operands; same regs)
            f4_t s[4];
            #pragma unroll
            for (int nh = 0; nh < 4; nh++) {
                const int key = nh * 16 + l16;
                const int ch0 = quad ^ (key & 7);
                const int ch1 = (4 + quad) ^ (key & 7);
                bf8_t k0f = *(const bf8_t*)(&Ks[cur][key * 64 + ch0 * 8]);
                bf8_t k1f = *(const bf8_t*)(&Ks[cur][key * 64 + ch1 * 8]);
                f4_t z = {0.f, 0.f, 0.f, 0.f};
                z = __builtin_amdgcn_mfma_f32_16x16x32_bf16(k0f, qa0, z, 0, 0, 0);
                z = __builtin_amdgcn_mfma_f32_16x16x32_bf16(k1f, qa1, z, 0, 0, 0);
                s[nh] = z;   // s[nh][r] = S[key=ktb+nh*16+quad*4+r][q=qrow]
            }

            // softmax numerator: p = exp2(s), packed bf16, swizzled b64 writes
            char* const psb = (char*)&Ps[w][0];
            #pragma unroll
            for (int nh = 0; nh < 4; nh++) {
                float v0 = s[nh][0], v1 = s[nh][1], v2 = s[nh][2], v3 = s[nh][3];
                if (domask) {
                    const int keyb = ktb + nh * 16 + quad * 4;
                    if (keyb     > qrow) v0 = -1e30f;
                    if (keyb + 1 > qrow) v1 = -1e30f;
                    if (keyb + 2 > qrow) v2 = -1e30f;
                    if (keyb + 3 > qrow) v3 = -1e30f;
                }
                u32x2 pk2;
                pk2.x = cvtpk(EXP2(v0), EXP2(v1));
                pk2.y = cvtpk(EXP2(v2), EXP2(v3));
                *(u32x2*)(psb + l16 * 128 + ((nh * 32 + quad * 8) ^ ((l16 & 7) << 4))) = pk2;
            }
            asm volatile("s_waitcnt lgkmcnt(0)" ::: "memory");

            // P A-frags: row = own q-row (l16), keys quad*8.. (swizzle-consistent)
            const bf8_t pa0 = *(const bf8_t*)(psb + l16 * 128 + ((quad * 16) ^ ((l16 & 7) << 4)));
            const bf8_t pa1 = *(const bf8_t*)(psb + l16 * 128 + ((64 + quad * 16) ^ ((l16 & 7) << 4)));

            // l += P @ 1 (row sums; replaces VALU adds + epilogue shuffle reduce)
            lacc = __builtin_amdgcn_mfma_f32_16x16x32_bf16(pa0, ones, lacc, 0, 0, 0);
            lacc = __builtin_amdgcn_mfma_f32_16x16x32_bf16(pa1, ones, lacc, 0, 0, 0);

            // O += P @ V
            #pragma unroll
            for (int nc = 0; nc < 4; nc++) {
                const int d = nc * 16 + l16;
                const int ch0 = quad ^ (d & 7);
                const int ch1 = (4 + quad) ^ (d & 7);
                bf8_t v0f = *(const bf8_t*)(&Vs[cur][d * 64 + ch0 * 8]);
                bf8_t v1f = *(const bf8_t*)(&Vs[cur][d * 64 + ch1 * 8]);
                o_acc[nc] = __builtin_amdgcn_mfma_f32_16x16x32_bf16(pa0, v0f, o_acc[nc], 0, 0, 0);
                o_acc[nc] = __builtin_amdgcn_mfma_f32_16x16x32_bf16(pa1, v1f, o_acc[nc], 0, 0, 0);
            }
        }
        __builtin_amdgcn_s_barrier();   // protect buf cur before next prefetch
    }
#undef STAGE

    // epilogue: O / l  (lacc rows == o_acc rows; no cross-lane work needed)
    #pragma unroll
    for (int r = 0; r < 4; r++) {
        const float rl = __builtin_amdgcn_rcpf(lacc[r]);
        const int row = wrow + quad * 4 + r;
        #pragma unroll
        for (int nc = 0; nc < 4; nc++) {
            ab[(size_t)(bb * T_ + row) * 1024 + hh * 64 + nc * 16 + l16] =
                f2b(o_acc[nc][r] * rl);
        }
    }
}

extern "C" void kernel_launch(void* const* d_in, const int* in_sizes, int n_in,
                              void* d_out, int out_size, void* d_ws, size_t ws_size,
                              hipStream_t stream) {
    const float* x    = (const float*)d_in[0];   // [4096,1024]
    const float* Wqkv = (const float*)d_in[1];   // [1024,3072]
    const float* bqkv = (const float*)d_in[2];   // [3072]
    const float* Wout = (const float*)d_in[3];   // [1024,1024]
    const float* bout = (const float*)d_in[4];   // [1024]
    float* out = (float*)d_out;                  // [4096,1024] fp32

    short* ws   = (short*)d_ws;
    short* xb   = ws;                                  // 4096*1024 (later: ab)
    short* wqt  = xb + (size_t)4096 * 1024;            // 3072*1024 (later: WoutT)
    short* qkvt = wqt + (size_t)3072 * 1024;           // 4096*3072
    short* vt   = (short*)d_out;                       // bf16 scratch in d_out
    short* ab   = xb;                                  // reuse xb after gemm_qkv

    // 1) cast x; transpose Wqkv (Q-rows pre-scaled by QS_ = 0.125*log2e)
    cast_f32_bf16<<<4096, 256, 0, stream>>>(x, xb);
    transpose_f2b<<<dim3(48, 16), 256, 0, stream>>>(Wqkv, wqt, 1024, 3072, 1024, QS_);

    // 2) QKV projection -> qkvt [4096][3072] bf16 (Q cols scaled, incl. bias)
    gemm_bt<<<dim3(24, 32), 256, 0, stream>>>(xb, wqt, bqkv, qkvt, nullptr,
                                              4096, 3072, 1024, 0, 1);

    // 3) V transpose -> vt ; Wout transpose (reuses wqt)
    transpose_v<<<dim3(32, 32), 256, 0, stream>>>(qkvt, vt);
    transpose_f2b<<<dim3(16, 16), 256, 0, stream>>>(Wout, wqt, 1024, 1024, 0, 1.0f);

    // 4) causal flash attention -> ab
    attn_kernel<<<1024, 256, 0, stream>>>(qkvt, vt, ab);

    // 5) output projection -> fp32 d_out (BN=64 tiles: 512 blocks, dbuf+vmcnt)
    gemm_bt_n64<<<dim3(16, 32), 256, 0, stream>>>(ab, wqt, bout, out,
                                                  4096, 1024, 1024);
}